// Round 10
// baseline (367.361 us; speedup 1.0000x reference)
//
#include <hip/hip_runtime.h>
#include <stdint.h>

#define BN 4
#define SEQ 2048
#define DM 1024
#define NH 16
#define HD 64
#define ROWS (BN*SEQ)   // 8192

typedef float  f32x4  __attribute__((ext_vector_type(4)));
typedef __bf16 bf16x8 __attribute__((ext_vector_type(8)));
typedef __bf16 bf16x4 __attribute__((ext_vector_type(4)));

#define QSCALE 0.18033688f   // log2(e)/8 — folded into Q projection epilogue

__device__ inline bf16x8 cvt8(const float* __restrict__ src) {
    float4 x0 = *(const float4*)src;
    float4 x1 = *(const float4*)(src + 4);
    bf16x8 r;
    r[0] = (__bf16)x0.x; r[1] = (__bf16)x0.y; r[2] = (__bf16)x0.z; r[3] = (__bf16)x0.w;
    r[4] = (__bf16)x1.x; r[5] = (__bf16)x1.y; r[6] = (__bf16)x1.z; r[7] = (__bf16)x1.w;
    return r;
}

// async global->LDS, 16B per lane; lds ptr wave-uniform (HW adds lane*16)
__device__ inline void gl_lds16(const void* g, void* l) {
    __builtin_amdgcn_global_load_lds((const __attribute__((address_space(1))) uint32_t*)g,
                                     (__attribute__((address_space(3))) uint32_t*)l, 16, 0, 0);
}

// ---------------- merged casts ----------------
__global__ __launch_bounds__(256) void cast3(
    const float* __restrict__ a0, const float* __restrict__ a1, const float* __restrict__ a2,
    __bf16* __restrict__ o0, __bf16* __restrict__ o1, __bf16* __restrict__ o2, int n8) {
    int t = blockIdx.x * 256 + threadIdx.x;
    if (t >= n8) return;
    const float* in = (blockIdx.y == 0) ? a0 : (blockIdx.y == 1) ? a1 : a2;
    __bf16* out     = (blockIdx.y == 0) ? o0 : (blockIdx.y == 1) ? o1 : o2;
    *(bf16x8*)&out[(size_t)t * 8] = cvt8(&in[(size_t)t * 8]);
}

__global__ __launch_bounds__(256) void cast4(
    const float* __restrict__ a0, const float* __restrict__ a1,
    const float* __restrict__ a2, const float* __restrict__ a3,
    __bf16* __restrict__ o0, __bf16* __restrict__ o1,
    __bf16* __restrict__ o2, __bf16* __restrict__ o3, int n8) {
    int t = blockIdx.x * 256 + threadIdx.x;
    if (t >= n8) return;
    const float* in = (blockIdx.y == 0) ? a0 : (blockIdx.y == 1) ? a1 : (blockIdx.y == 2) ? a2 : a3;
    __bf16* out     = (blockIdx.y == 0) ? o0 : (blockIdx.y == 1) ? o1 : (blockIdx.y == 2) ? o2 : o3;
    *(bf16x8*)&out[(size_t)t * 8] = cvt8(&in[(size_t)t * 8]);
}

// ======================================================================
// FAST PATH GEMMs: bf16 A and B staged via global_load_lds (m97 structure)
// 128x128 tile, BK=32, As/Bs unpadded [128][32].
// ======================================================================
#define GEMM_CORE_GLDS(Xp, Wp)                                                     \
    __shared__ __align__(16) __bf16 As[128 * 32];                                  \
    __shared__ __align__(16) __bf16 Bs[128 * 32];                                  \
    const int tid  = threadIdx.x;                                                  \
    const int lane = tid & 63;                                                     \
    const int wave = tid >> 6;                                                     \
    const int wm = (wave >> 1) * 64;                                               \
    const int wn = (wave & 1) * 64;                                                \
    const int c16 = lane & 15;                                                     \
    const int g8  = (lane >> 4) * 8;                                               \
    const int row0 = blockIdx.x * 128;                                             \
    const int col0 = blockIdx.y * 128;                                             \
    f32x4 acc[4][4] = {};                                                          \
    for (int k0 = 0; k0 < DM; k0 += 32) {                                          \
        __syncthreads();                                                           \
        _Pragma("unroll")                                                          \
        for (int h = 0; h < 2; h++) {                                              \
            int cidx = h * 256 + tid;                                              \
            gl_lds16(&Xp[(size_t)(row0 + (cidx >> 2)) * DM + k0 + (cidx & 3) * 8], \
                     &As[(size_t)(h * 256 + wave * 64) * 8]);                      \
            gl_lds16(&Wp[(size_t)(col0 + (cidx >> 2)) * DM + k0 + (cidx & 3) * 8], \
                     &Bs[(size_t)(h * 256 + wave * 64) * 8]);                      \
        }                                                                          \
        __syncthreads();                                                           \
        bf16x8 a[4], bfr[4];                                                       \
        _Pragma("unroll")                                                          \
        for (int i = 0; i < 4; i++) a[i]   = *(const bf16x8*)&As[(wm + i * 16 + c16) * 32 + g8]; \
        _Pragma("unroll")                                                          \
        for (int i = 0; i < 4; i++) bfr[i] = *(const bf16x8*)&Bs[(wn + i * 16 + c16) * 32 + g8]; \
        _Pragma("unroll")                                                          \
        for (int mi = 0; mi < 4; mi++)                                             \
            _Pragma("unroll")                                                      \
            for (int ni = 0; ni < 4; ni++)                                         \
                acc[mi][ni] = __builtin_amdgcn_mfma_f32_16x16x32_bf16(a[mi], bfr[ni], acc[mi][ni], 0, 0, 0); \
    }

// merged Q/K/V projection: z=0 -> Qp (pre-scaled), z=1 -> Kp, z=2 -> Vt^T
__global__ __launch_bounds__(256) void gemm_qkv_f(
    const __bf16* __restrict__ qb, const __bf16* __restrict__ kb,
    const __bf16* __restrict__ vb,
    const __bf16* __restrict__ wqb, const __bf16* __restrict__ wkb,
    const __bf16* __restrict__ wvb,
    const float* __restrict__ bq, const float* __restrict__ bk,
    const float* __restrict__ bv,
    __bf16* __restrict__ Qp, __bf16* __restrict__ Kp, __bf16* __restrict__ Vt)
{
    const int z = blockIdx.z;
    const __bf16* X = (z == 0) ? qb : (z == 1) ? kb : vb;
    const __bf16* W = (z == 0) ? wqb : (z == 1) ? wkb : wvb;
    const float* bias = (z == 0) ? bq : (z == 1) ? bk : bv;

    GEMM_CORE_GLDS(X, W)

    if (z < 2) {
        __bf16* O = z ? Kp : Qp;
        const float qsc = z ? 1.0f : QSCALE;   // pre-scale Q by log2(e)/8
        #pragma unroll
        for (int mi = 0; mi < 4; mi++) {
            int r0 = row0 + wm + mi * 16 + (lane >> 4) * 4;
            #pragma unroll
            for (int ni = 0; ni < 4; ni++) {
                int col = col0 + wn + ni * 16 + c16;
                float bsv = bias[col];
                int h = col >> 6, d = col & 63;
                #pragma unroll
                for (int i = 0; i < 4; i++) {
                    int r = r0 + i; int b = r >> 11, s = r & 2047;
                    O[((size_t)(b * NH + h) * SEQ + s) * HD + d] = (__bf16)((acc[mi][ni][i] + bsv) * qsc);
                }
            }
        }
    } else {
        #pragma unroll
        for (int mi = 0; mi < 4; mi++) {
            int r0 = row0 + wm + mi * 16 + (lane >> 4) * 4;
            #pragma unroll
            for (int ni = 0; ni < 4; ni++) {
                int col = col0 + wn + ni * 16 + c16;
                float bsv = bias[col];
                int h = col >> 6, d = col & 63;
                int b = r0 >> 11, s0 = r0 & 2047;
                size_t base = ((size_t)((b * NH + h) * HD + d)) * SEQ + s0;
                #pragma unroll
                for (int i = 0; i < 4; i++)
                    Vt[base + i] = (__bf16)(acc[mi][ni][i] + bsv);
            }
        }
    }
}

// FC: 128x64 tile, grid (64,16) = 1024 blocks = 4/CU (was 512 = 2/CU,
// latency-starved at 2 waves/SIMD). Wave: 64x32 output, acc[4][2].
__global__ __launch_bounds__(256) void gemm_fc_f(
    const __bf16* __restrict__ Xc, const __bf16* __restrict__ Wfb,
    const float* __restrict__ bias, float* __restrict__ out)
{
    __shared__ __align__(16) __bf16 As[128 * 32];
    __shared__ __align__(16) __bf16 Bs[64 * 32];

    const int tid  = threadIdx.x;
    const int lane = tid & 63;
    const int wave = tid >> 6;
    const int wm = (wave >> 1) * 64;
    const int wn = (wave & 1) * 32;
    const int c16 = lane & 15;
    const int g8  = (lane >> 4) * 8;
    const int row0 = blockIdx.x * 128;
    const int col0 = blockIdx.y * 64;

    f32x4 acc[4][2] = {};
    for (int k0 = 0; k0 < DM; k0 += 32) {
        __syncthreads();
        #pragma unroll
        for (int h = 0; h < 2; h++) {
            int cidx = h * 256 + tid;
            gl_lds16(&Xc[(size_t)(row0 + (cidx >> 2)) * DM + k0 + (cidx & 3) * 8],
                     &As[(size_t)(h * 256 + wave * 64) * 8]);
        }
        // B: 64 rows x 32 cols = 4KB = one 256-lane round
        gl_lds16(&Wfb[(size_t)(col0 + (tid >> 2)) * DM + k0 + (tid & 3) * 8],
                 &Bs[(size_t)(wave * 64) * 8]);
        __syncthreads();

        bf16x8 a[4], bfr[2];
        #pragma unroll
        for (int i = 0; i < 4; i++) a[i]   = *(const bf16x8*)&As[(wm + i * 16 + c16) * 32 + g8];
        #pragma unroll
        for (int i = 0; i < 2; i++) bfr[i] = *(const bf16x8*)&Bs[(wn + i * 16 + c16) * 32 + g8];
        #pragma unroll
        for (int mi = 0; mi < 4; mi++)
            #pragma unroll
            for (int ni = 0; ni < 2; ni++)
                acc[mi][ni] = __builtin_amdgcn_mfma_f32_16x16x32_bf16(a[mi], bfr[ni], acc[mi][ni], 0, 0, 0);
    }

    #pragma unroll
    for (int mi = 0; mi < 4; mi++) {
        int r0 = row0 + wm + mi * 16 + (lane >> 4) * 4;
        #pragma unroll
        for (int ni = 0; ni < 2; ni++) {
            int col = col0 + wn + ni * 16 + c16;
            float bsv = bias[col];
            #pragma unroll
            for (int i = 0; i < 4; i++)
                out[(size_t)(r0 + i) * DM + col] = acc[mi][ni][i] + bsv;
        }
    }
}

// ======================================================================
// FALLBACK GEMMs (known-good, ws = 67 MB)
// ======================================================================
__global__ __launch_bounds__(256) void gemm_qk(
    const __bf16* __restrict__ qb, const __bf16* __restrict__ kb,
    const float* __restrict__ wqf, const float* __restrict__ wkf,
    const float* __restrict__ bq, const float* __restrict__ bk,
    __bf16* __restrict__ Qp, __bf16* __restrict__ Kp)
{
    const int z = blockIdx.z;
    const __bf16* X = z ? kb : qb;
    const float* W  = z ? wkf : wqf;
    const float* bias = z ? bk : bq;
    __bf16* O = z ? Kp : Qp;
    const float qsc = z ? 1.0f : QSCALE;

    __shared__ __align__(16) __bf16 As[128 * 32];
    __shared__ __align__(16) __bf16 Bs[128 * 32];

    const int tid  = threadIdx.x;
    const int lane = tid & 63;
    const int wave = tid >> 6;
    const int wm = (wave >> 1) * 64;
    const int wn = (wave & 1) * 64;
    const int c16 = lane & 15;
    const int g8  = (lane >> 4) * 8;
    const int row0 = blockIdx.x * 128;
    const int col0 = blockIdx.y * 128;
    const int brow = tid >> 1;
    const int bcc  = (tid & 1) * 16;

    f32x4 acc[4][4] = {};
    for (int k0 = 0; k0 < DM; k0 += 32) {
        __syncthreads();
        #pragma unroll
        for (int h = 0; h < 2; h++) {
            int cidx = h * 256 + tid;
            gl_lds16(&X[(size_t)(row0 + (cidx >> 2)) * DM + k0 + (cidx & 3) * 8],
                     &As[(size_t)(h * 256 + wave * 64) * 8]);
        }
        *(bf16x8*)&Bs[brow * 32 + bcc]     = cvt8(&W[(size_t)(col0 + brow) * DM + k0 + bcc]);
        *(bf16x8*)&Bs[brow * 32 + bcc + 8] = cvt8(&W[(size_t)(col0 + brow) * DM + k0 + bcc + 8]);
        __syncthreads();

        bf16x8 a[4], bfr[4];
        #pragma unroll
        for (int i = 0; i < 4; i++) a[i]   = *(const bf16x8*)&As[(wm + i * 16 + c16) * 32 + g8];
        #pragma unroll
        for (int i = 0; i < 4; i++) bfr[i] = *(const bf16x8*)&Bs[(wn + i * 16 + c16) * 32 + g8];
        #pragma unroll
        for (int mi = 0; mi < 4; mi++)
            #pragma unroll
            for (int ni = 0; ni < 4; ni++)
                acc[mi][ni] = __builtin_amdgcn_mfma_f32_16x16x32_bf16(a[mi], bfr[ni], acc[mi][ni], 0, 0, 0);
    }

    #pragma unroll
    for (int mi = 0; mi < 4; mi++) {
        int r0 = row0 + wm + mi * 16 + (lane >> 4) * 4;
        #pragma unroll
        for (int ni = 0; ni < 4; ni++) {
            int col = col0 + wn + ni * 16 + c16;
            float bsv = bias[col];
            int h = col >> 6, d = col & 63;
            #pragma unroll
            for (int i = 0; i < 4; i++) {
                int r = r0 + i; int b = r >> 11, s = r & 2047;
                O[((size_t)(b * NH + h) * SEQ + s) * HD + d] = (__bf16)((acc[mi][ni][i] + bsv) * qsc);
            }
        }
    }
}

__global__ __launch_bounds__(256) void gemm_v(
    const float* __restrict__ vf, const float* __restrict__ wvf,
    const float* __restrict__ bv, __bf16* __restrict__ Vt)
{
    __shared__ __align__(16) __bf16 As[128 * 32];
    __shared__ __align__(16) __bf16 Bs[128 * 32];

    const int tid  = threadIdx.x;
    const int lane = tid & 63;
    const int wave = tid >> 6;
    const int wm = (wave >> 1) * 64;
    const int wn = (wave & 1) * 64;
    const int c16 = lane & 15;
    const int g8  = (lane >> 4) * 8;
    const int row0 = blockIdx.x * 128;
    const int col0 = blockIdx.y * 128;
    const int brow = tid >> 1;
    const int bcc  = (tid & 1) * 16;

    f32x4 acc[4][4] = {};
    for (int k0 = 0; k0 < DM; k0 += 32) {
        __syncthreads();
        *(bf16x8*)&As[brow * 32 + bcc]     = cvt8(&vf[(size_t)(row0 + brow) * DM + k0 + bcc]);
        *(bf16x8*)&As[brow * 32 + bcc + 8] = cvt8(&vf[(size_t)(row0 + brow) * DM + k0 + bcc + 8]);
        *(bf16x8*)&Bs[brow * 32 + bcc]     = cvt8(&wvf[(size_t)(col0 + brow) * DM + k0 + bcc]);
        *(bf16x8*)&Bs[brow * 32 + bcc + 8] = cvt8(&wvf[(size_t)(col0 + brow) * DM + k0 + bcc + 8]);
        __syncthreads();

        bf16x8 a[4], bfr[4];
        #pragma unroll
        for (int i = 0; i < 4; i++) a[i]   = *(const bf16x8*)&As[(wm + i * 16 + c16) * 32 + g8];
        #pragma unroll
        for (int i = 0; i < 4; i++) bfr[i] = *(const bf16x8*)&Bs[(wn + i * 16 + c16) * 32 + g8];
        #pragma unroll
        for (int mi = 0; mi < 4; mi++)
            #pragma unroll
            for (int ni = 0; ni < 4; ni++)
                acc[mi][ni] = __builtin_amdgcn_mfma_f32_16x16x32_bf16(a[mi], bfr[ni], acc[mi][ni], 0, 0, 0);
    }

    #pragma unroll
    for (int mi = 0; mi < 4; mi++) {
        int r0 = row0 + wm + mi * 16 + (lane >> 4) * 4;
        #pragma unroll
        for (int ni = 0; ni < 4; ni++) {
            int col = col0 + wn + ni * 16 + c16;
            float bsv = bv[col];
            int h = col >> 6, d = col & 63;
            int b = r0 >> 11, s0 = r0 & 2047;
            size_t base = ((size_t)((b * NH + h) * HD + d)) * SEQ + s0;
            #pragma unroll
            for (int i = 0; i < 4; i++)
                Vt[base + i] = (__bf16)(acc[mi][ni][i] + bsv);
        }
    }
}

__global__ __launch_bounds__(256) void gemm_fc(
    const __bf16* __restrict__ Xc, const float* __restrict__ Wf,
    const float* __restrict__ bias, float* __restrict__ out)
{
    __shared__ __align__(16) __bf16 As[128 * 32];
    __shared__ __align__(16) __bf16 Bs[128 * 32];

    const int tid  = threadIdx.x;
    const int lane = tid & 63;
    const int wave = tid >> 6;
    const int wm = (wave >> 1) * 64;
    const int wn = (wave & 1) * 64;
    const int c16 = lane & 15;
    const int g8  = (lane >> 4) * 8;
    const int row0 = blockIdx.x * 128;
    const int col0 = blockIdx.y * 128;
    const int brow = tid >> 1;
    const int bcc  = (tid & 1) * 16;

    f32x4 acc[4][4] = {};
    for (int k0 = 0; k0 < DM; k0 += 32) {
        __syncthreads();
        #pragma unroll
        for (int h = 0; h < 2; h++) {
            int cidx = h * 256 + tid;
            gl_lds16(&Xc[(size_t)(row0 + (cidx >> 2)) * DM + k0 + (cidx & 3) * 8],
                     &As[(size_t)(h * 256 + wave * 64) * 8]);
        }
        *(bf16x8*)&Bs[brow * 32 + bcc]     = cvt8(&Wf[(size_t)(col0 + brow) * DM + k0 + bcc]);
        *(bf16x8*)&Bs[brow * 32 + bcc + 8] = cvt8(&Wf[(size_t)(col0 + brow) * DM + k0 + bcc + 8]);
        __syncthreads();

        bf16x8 a[4], bfr[4];
        #pragma unroll
        for (int i = 0; i < 4; i++) a[i]   = *(const bf16x8*)&As[(wm + i * 16 + c16) * 32 + g8];
        #pragma unroll
        for (int i = 0; i < 4; i++) bfr[i] = *(const bf16x8*)&Bs[(wn + i * 16 + c16) * 32 + g8];
        #pragma unroll
        for (int mi = 0; mi < 4; mi++)
            #pragma unroll
            for (int ni = 0; ni < 4; ni++)
                acc[mi][ni] = __builtin_amdgcn_mfma_f32_16x16x32_bf16(a[mi], bfr[ni], acc[mi][ni], 0, 0, 0);
    }

    #pragma unroll
    for (int mi = 0; mi < 4; mi++) {
        int r0 = row0 + wm + mi * 16 + (lane >> 4) * 4;
        #pragma unroll
        for (int ni = 0; ni < 4; ni++) {
            int col = col0 + wn + ni * 16 + c16;
            float bsv = bias[col];
            #pragma unroll
            for (int i = 0; i < 4; i++)
                out[(size_t)(r0 + i) * DM + col] = acc[mi][ni][i] + bsv;
        }
    }
}

// ======================================================================
// flash attention (S^T / O^T), XOR-swizzled LDS, one-pass softmax.
// R9 structure (16x16 MFMA, 4-wave, single-buffered, QSCALE fold,
// transposed grid, permuted-k PV contract, 16KB LDS) + T5 setprio
// around both MFMA clusters (m191: +4-7% attn when blocks at mixed
// phases share a CU; harmless if null).
// grid (B*H, SEQ/128), block 256 = 4 waves; wave owns 32 queries.
// ======================================================================
__global__ __launch_bounds__(256, 4) void attn_kernel(
    const __bf16* __restrict__ Qp, const __bf16* __restrict__ Kp,
    const __bf16* __restrict__ Vt, __bf16* __restrict__ ctx)
{
    __shared__ __align__(16) __bf16 Ks[64 * 64];        // [key][d], swizzled
    __shared__ __align__(16) __bf16 Vs[64 * 64];        // [d][key], swizzled

    const int tid  = threadIdx.x;
    const int lane = tid & 63;
    const int w    = tid >> 6;
    const int bh   = blockIdx.x;                        // head index (XCD-local)
    const int q0   = blockIdx.y * 128 + w * 32;

    const __bf16* Qb = Qp + (size_t)bh * SEQ * HD;
    const __bf16* Kb = Kp + (size_t)bh * SEQ * HD;
    const __bf16* Vb = Vt + (size_t)bh * HD * SEQ;

    const int c16 = lane & 15;
    const int g   = lane >> 4;
    const int sw  = c16 & 7;    // swizzle key for this lane's frag rows

    // Q as B-fragment of Q^T: lane holds Q[query=c16][k = kc*32 + g*8 + j]
    bf16x8 qf[2][2];
    #pragma unroll
    for (int qs = 0; qs < 2; qs++)
        #pragma unroll
        for (int kc = 0; kc < 2; kc++)
            qf[qs][kc] = *(const bf16x8*)&Qb[(size_t)(q0 + qs * 16 + c16) * HD + kc * 32 + g * 8];

    float lp[2] = {0.f, 0.f};
    f32x4 o[4][2] = {};                 // O^T: row d = t*16+g*4+i, col query = c16

    // GLDS staging: wave w stages rows w*16 .. w*16+15 of Ks and Vs.
    const int srow = (w * 16) + (lane >> 3);          // +8 for h=1
    const int sj   = (lane & 7) ^ (lane >> 3);        // logical chunk (XOR swizzle)

    for (int kt = 0; kt < SEQ / 64; kt++) {
        const int k0 = kt * 64;
        __syncthreads();
        #pragma unroll
        for (int h = 0; h < 2; h++) {
            int r = srow + h * 8;
            gl_lds16(&Kb[(size_t)(k0 + r) * HD + sj * 8], &Ks[(size_t)(w * 16 + h * 8) * 64]);
            gl_lds16(&Vb[(size_t)r * SEQ + k0 + sj * 8],  &Vs[(size_t)(w * 16 + h * 8) * 64]);
        }
        __syncthreads();

        // S^T = K · Q^T : rows = keys, cols = queries
        f32x4 sc[4][2] = {};
        __builtin_amdgcn_s_setprio(1);
        #pragma unroll
        for (int t = 0; t < 4; t++) {
            #pragma unroll
            for (int kc = 0; kc < 2; kc++) {
                bf16x8 kf = *(const bf16x8*)&Ks[(t * 16 + c16) * 64 + ((kc * 4 + g) ^ sw) * 8];
                sc[t][0] = __builtin_amdgcn_mfma_f32_16x16x32_bf16(kf, qf[0][kc], sc[t][0], 0, 0, 0);
                sc[t][1] = __builtin_amdgcn_mfma_f32_16x16x32_bf16(kf, qf[1][kc], sc[t][1], 0, 0, 0);
            }
        }
        __builtin_amdgcn_s_setprio(0);

        // softmax + permuted-k B-frag pack, fully in-register:
        // pf[qs][kc][j] = exp2(sc[2kc + (j>=4)][qs][j&3])
        bf16x8 pf[2][2];
        #pragma unroll
        for (int qs = 0; qs < 2; qs++) {
            float ps = 0.f;
            #pragma unroll
            for (int kc = 0; kc < 2; kc++) {
                bf16x8 pv8;
                #pragma unroll
                for (int i = 0; i < 4; i++) {
                    float pv = exp2f(sc[2 * kc][qs][i]);
                    ps += pv; pv8[i] = (__bf16)pv;
                }
                #pragma unroll
                for (int i = 0; i < 4; i++) {
                    float pv = exp2f(sc[2 * kc + 1][qs][i]);
                    ps += pv; pv8[4 + i] = (__bf16)pv;
                }
                pf[qs][kc] = pv8;
            }
            lp[qs] += ps;
        }

        // O^T += V^T · P^T with permuted-k A reads:
        // slot (g, j<4)  -> key kc*32 + 4g + j    (chunk kc*4+(g>>1),   elem (g&1)*4)
        // slot (g, j>=4) -> key kc*32 + 16+4g+j-4 (chunk kc*4+2+(g>>1), elem (g&1)*4)
        __builtin_amdgcn_s_setprio(1);
        #pragma unroll
        for (int t = 0; t < 4; t++) {
            #pragma unroll
            for (int kc = 0; kc < 2; kc++) {
                union { bf16x8 v8; bf16x4 v4[2]; } u;
                u.v4[0] = *(const bf16x4*)&Vs[(t * 16 + c16) * 64 + (((kc * 4 + (g >> 1)) ^ sw) * 8) + (g & 1) * 4];
                u.v4[1] = *(const bf16x4*)&Vs[(t * 16 + c16) * 64 + (((kc * 4 + 2 + (g >> 1)) ^ sw) * 8) + (g & 1) * 4];
                o[t][0] = __builtin_amdgcn_mfma_f32_16x16x32_bf16(u.v8, pf[0][kc], o[t][0], 0, 0, 0);
                o[t][1] = __builtin_amdgcn_mfma_f32_16x16x32_bf16(u.v8, pf[1][kc], o[t][1], 0, 0, 0);
            }
        }
        __builtin_amdgcn_s_setprio(0);
    }

    // finalize: reduce l over the 4 g-lanes, normalize, write ctx
    const int hh = bh & (NH - 1);
    const int bb = bh >> 4;
    #pragma unroll
    for (int qs = 0; qs < 2; qs++) {
        float l = lp[qs];
        l += __shfl_xor(l, 16, 64);
        l += __shfl_xor(l, 32, 64);
        float inv = 1.f / l;
        int s = q0 + qs * 16 + c16;
        #pragma unroll
        for (int t = 0; t < 4; t++) {
            bf16x4 ov;
            #pragma unroll
            for (int i = 0; i < 4; i++) ov[i] = (__bf16)(o[t][qs][i] * inv);
            *(bf16x4*)&ctx[((size_t)(bb * SEQ + s)) * DM + hh * HD + t * 16 + g * 4] = ov;
        }
    }
}

// ---------------- launch ----------------
extern "C" void kernel_launch(void* const* d_in, const int* in_sizes, int n_in,
                              void* d_out, int out_size, void* d_ws, size_t ws_size,
                              hipStream_t stream) {
    const float* q    = (const float*)d_in[0];
    const float* k    = (const float*)d_in[1];
    const float* v    = (const float*)d_in[2];
    const float* w_q  = (const float*)d_in[3];
    const float* b_q  = (const float*)d_in[4];
    const float* w_k  = (const float*)d_in[5];
    const float* b_k  = (const float*)d_in[6];
    const float* w_v  = (const float*)d_in[7];
    const float* b_v  = (const float*)d_in[8];
    const float* w_fc = (const float*)d_in[9];
    const float* b_fc = (const float*)d_in[10];
    float* out = (float*)d_out;

    // qb,kb live in d_out (dead before gemm_fc writes it)
    __bf16* qb = (__bf16*)d_out;
    __bf16* kb = qb + (size_t)ROWS * DM;

    char* p = (char*)d_ws;
    auto alloc = [&](size_t bytes) { char* r = p; p += (bytes + 255) & ~(size_t)255; return r; };
    const size_t XSZ = (size_t)ROWS * DM * 2;   // 16.78 MB
    const size_t WSZ = (size_t)DM * DM * 2;     // 2.10 MB

    __bf16* Qp  = (__bf16*)alloc(XSZ);
    __bf16* Kp  = (__bf16*)alloc(XSZ);
    __bf16* Vt  = (__bf16*)alloc(XSZ);
    __bf16* ctx = (__bf16*)alloc(XSZ);

    const size_t base_need = (size_t)(p - (char*)d_ws);
    const size_t fast_need = base_need + 4 * (WSZ + 256);

    const int n8x = ROWS * DM / 8;   // 1,048,576
    const int n8w = DM * DM / 8;     // 131,072

    // vb lives in the ctx region: dead before attn writes ctx, and does NOT
    // alias Qp -> enables the single merged QKV projection launch.
    __bf16* vb = ctx;

    // q,k -> d_out region; v -> ctx region (one merged launch)
    cast3<<<dim3(n8x / 256, 3), 256, 0, stream>>>(q, k, v, qb, kb, vb, n8x);

    if (ws_size >= fast_need) {
        // FAST PATH: bf16 weights in ws, all GEMMs all-GLDS.
        __bf16* wqb  = (__bf16*)alloc(WSZ);
        __bf16* wkb  = (__bf16*)alloc(WSZ);
        __bf16* wvb  = (__bf16*)alloc(WSZ);
        __bf16* wfcb = (__bf16*)alloc(WSZ);

        cast4<<<dim3(n8w / 256, 4), 256, 0, stream>>>(
            w_q, w_k, w_v, w_fc, wqb, wkb, wvb, wfcb, n8w);

        // merged Q/K/V projections: one 1536-block launch (6 blocks/CU)
        gemm_qkv_f<<<dim3(ROWS / 128, DM / 128, 3), 256, 0, stream>>>(
            qb, kb, vb, wqb, wkb, wvb, b_q, b_k, b_v, Qp, Kp, Vt);

        // grid: x = head (XCD-local K/V), y = q-block (128 queries)
        attn_kernel<<<dim3(BN * NH, SEQ / 128), 256, 0, stream>>>(Qp, Kp, Vt, ctx);

        // FC: 128x64 tiles -> 1024 blocks (4/CU)
        gemm_fc_f<<<dim3(ROWS / 128, DM / 64), 256, 0, stream>>>(ctx, wfcb, b_fc, out);
    } else {
        // FALLBACK (67 MB ws)
        gemm_v<<<dim3(ROWS / 128, DM / 128), 256, 0, stream>>>(v, w_v, b_v, Vt);
        gemm_qk<<<dim3(ROWS / 128, DM / 128, 2), 256, 0, stream>>>(
            qb, kb, w_q, w_k, b_q, b_k, Qp, Kp);

        attn_kernel<<<dim3(BN * NH, SEQ / 128), 256, 0, stream>>>(Qp, Kp, Vt, ctx);

        gemm_fc<<<dim3(ROWS / 128, DM / 128), 256, 0, stream>>>(ctx, w_fc, b_fc, out);
    }
}

// Round 11
// 360.191 us; speedup vs baseline: 1.0199x; 1.0199x over previous
//
#include <hip/hip_runtime.h>
#include <stdint.h>

#define BN 4
#define SEQ 2048
#define DM 1024
#define NH 16
#define HD 64
#define ROWS (BN*SEQ)   // 8192

typedef float  f32x4  __attribute__((ext_vector_type(4)));
typedef __bf16 bf16x8 __attribute__((ext_vector_type(8)));
typedef __bf16 bf16x4 __attribute__((ext_vector_type(4)));

#define QSCALE 0.18033688f   // log2(e)/8 — folded into Q projection epilogue

__device__ inline bf16x8 cvt8(const float* __restrict__ src) {
    float4 x0 = *(const float4*)src;
    float4 x1 = *(const float4*)(src + 4);
    bf16x8 r;
    r[0] = (__bf16)x0.x; r[1] = (__bf16)x0.y; r[2] = (__bf16)x0.z; r[3] = (__bf16)x0.w;
    r[4] = (__bf16)x1.x; r[5] = (__bf16)x1.y; r[6] = (__bf16)x1.z; r[7] = (__bf16)x1.w;
    return r;
}

// async global->LDS, 16B per lane; lds ptr wave-uniform (HW adds lane*16)
__device__ inline void gl_lds16(const void* g, void* l) {
    __builtin_amdgcn_global_load_lds((const __attribute__((address_space(1))) uint32_t*)g,
                                     (__attribute__((address_space(3))) uint32_t*)l, 16, 0, 0);
}

// ---------------- merged casts ----------------
__global__ __launch_bounds__(256) void cast3(
    const float* __restrict__ a0, const float* __restrict__ a1, const float* __restrict__ a2,
    __bf16* __restrict__ o0, __bf16* __restrict__ o1, __bf16* __restrict__ o2, int n8) {
    int t = blockIdx.x * 256 + threadIdx.x;
    if (t >= n8) return;
    const float* in = (blockIdx.y == 0) ? a0 : (blockIdx.y == 1) ? a1 : a2;
    __bf16* out     = (blockIdx.y == 0) ? o0 : (blockIdx.y == 1) ? o1 : o2;
    *(bf16x8*)&out[(size_t)t * 8] = cvt8(&in[(size_t)t * 8]);
}

__global__ __launch_bounds__(256) void cast4(
    const float* __restrict__ a0, const float* __restrict__ a1,
    const float* __restrict__ a2, const float* __restrict__ a3,
    __bf16* __restrict__ o0, __bf16* __restrict__ o1,
    __bf16* __restrict__ o2, __bf16* __restrict__ o3, int n8) {
    int t = blockIdx.x * 256 + threadIdx.x;
    if (t >= n8) return;
    const float* in = (blockIdx.y == 0) ? a0 : (blockIdx.y == 1) ? a1 : (blockIdx.y == 2) ? a2 : a3;
    __bf16* out     = (blockIdx.y == 0) ? o0 : (blockIdx.y == 1) ? o1 : (blockIdx.y == 2) ? o2 : o3;
    *(bf16x8*)&out[(size_t)t * 8] = cvt8(&in[(size_t)t * 8]);
}

// ======================================================================
// FAST PATH GEMMs: bf16 A and B staged via global_load_lds (m97 structure)
// 128x128 tile, BK=32, As/Bs unpadded [128][32].
// ======================================================================
#define GEMM_CORE_GLDS(Xp, Wp)                                                     \
    __shared__ __align__(16) __bf16 As[128 * 32];                                  \
    __shared__ __align__(16) __bf16 Bs[128 * 32];                                  \
    const int tid  = threadIdx.x;                                                  \
    const int lane = tid & 63;                                                     \
    const int wave = tid >> 6;                                                     \
    const int wm = (wave >> 1) * 64;                                               \
    const int wn = (wave & 1) * 64;                                                \
    const int c16 = lane & 15;                                                     \
    const int g8  = (lane >> 4) * 8;                                               \
    const int row0 = blockIdx.x * 128;                                             \
    const int col0 = blockIdx.y * 128;                                             \
    f32x4 acc[4][4] = {};                                                          \
    for (int k0 = 0; k0 < DM; k0 += 32) {                                          \
        __syncthreads();                                                           \
        _Pragma("unroll")                                                          \
        for (int h = 0; h < 2; h++) {                                              \
            int cidx = h * 256 + tid;                                              \
            gl_lds16(&Xp[(size_t)(row0 + (cidx >> 2)) * DM + k0 + (cidx & 3) * 8], \
                     &As[(size_t)(h * 256 + wave * 64) * 8]);                      \
            gl_lds16(&Wp[(size_t)(col0 + (cidx >> 2)) * DM + k0 + (cidx & 3) * 8], \
                     &Bs[(size_t)(h * 256 + wave * 64) * 8]);                      \
        }                                                                          \
        __syncthreads();                                                           \
        bf16x8 a[4], bfr[4];                                                       \
        _Pragma("unroll")                                                          \
        for (int i = 0; i < 4; i++) a[i]   = *(const bf16x8*)&As[(wm + i * 16 + c16) * 32 + g8]; \
        _Pragma("unroll")                                                          \
        for (int i = 0; i < 4; i++) bfr[i] = *(const bf16x8*)&Bs[(wn + i * 16 + c16) * 32 + g8]; \
        _Pragma("unroll")                                                          \
        for (int mi = 0; mi < 4; mi++)                                             \
            _Pragma("unroll")                                                      \
            for (int ni = 0; ni < 4; ni++)                                         \
                acc[mi][ni] = __builtin_amdgcn_mfma_f32_16x16x32_bf16(a[mi], bfr[ni], acc[mi][ni], 0, 0, 0); \
    }

// merged Q/K/V projection: z=0 -> Qp (pre-scaled), z=1 -> Kp, z=2 -> Vt^T
__global__ __launch_bounds__(256) void gemm_qkv_f(
    const __bf16* __restrict__ qb, const __bf16* __restrict__ kb,
    const __bf16* __restrict__ vb,
    const __bf16* __restrict__ wqb, const __bf16* __restrict__ wkb,
    const __bf16* __restrict__ wvb,
    const float* __restrict__ bq, const float* __restrict__ bk,
    const float* __restrict__ bv,
    __bf16* __restrict__ Qp, __bf16* __restrict__ Kp, __bf16* __restrict__ Vt)
{
    const int z = blockIdx.z;
    const __bf16* X = (z == 0) ? qb : (z == 1) ? kb : vb;
    const __bf16* W = (z == 0) ? wqb : (z == 1) ? wkb : wvb;
    const float* bias = (z == 0) ? bq : (z == 1) ? bk : bv;

    GEMM_CORE_GLDS(X, W)

    if (z < 2) {
        __bf16* O = z ? Kp : Qp;
        const float qsc = z ? 1.0f : QSCALE;   // pre-scale Q by log2(e)/8
        #pragma unroll
        for (int mi = 0; mi < 4; mi++) {
            int r0 = row0 + wm + mi * 16 + (lane >> 4) * 4;
            #pragma unroll
            for (int ni = 0; ni < 4; ni++) {
                int col = col0 + wn + ni * 16 + c16;
                float bsv = bias[col];
                int h = col >> 6, d = col & 63;
                #pragma unroll
                for (int i = 0; i < 4; i++) {
                    int r = r0 + i; int b = r >> 11, s = r & 2047;
                    O[((size_t)(b * NH + h) * SEQ + s) * HD + d] = (__bf16)((acc[mi][ni][i] + bsv) * qsc);
                }
            }
        }
    } else {
        #pragma unroll
        for (int mi = 0; mi < 4; mi++) {
            int r0 = row0 + wm + mi * 16 + (lane >> 4) * 4;
            #pragma unroll
            for (int ni = 0; ni < 4; ni++) {
                int col = col0 + wn + ni * 16 + c16;
                float bsv = bias[col];
                int h = col >> 6, d = col & 63;
                int b = r0 >> 11, s0 = r0 & 2047;
                size_t base = ((size_t)((b * NH + h) * HD + d)) * SEQ + s0;
                #pragma unroll
                for (int i = 0; i < 4; i++)
                    Vt[base + i] = (__bf16)(acc[mi][ni][i] + bsv);
            }
        }
    }
}

// FC: 128x64 tile, grid (64,16) = 1024 blocks = 4/CU (vs 512 = 2/CU,
// latency-starved at 2 waves/SIMD). Wave: 64x32 output, acc[4][2].
__global__ __launch_bounds__(256) void gemm_fc_f(
    const __bf16* __restrict__ Xc, const __bf16* __restrict__ Wfb,
    const float* __restrict__ bias, float* __restrict__ out)
{
    __shared__ __align__(16) __bf16 As[128 * 32];
    __shared__ __align__(16) __bf16 Bs[64 * 32];

    const int tid  = threadIdx.x;
    const int lane = tid & 63;
    const int wave = tid >> 6;
    const int wm = (wave >> 1) * 64;
    const int wn = (wave & 1) * 32;
    const int c16 = lane & 15;
    const int g8  = (lane >> 4) * 8;
    const int row0 = blockIdx.x * 128;
    const int col0 = blockIdx.y * 64;

    f32x4 acc[4][2] = {};
    for (int k0 = 0; k0 < DM; k0 += 32) {
        __syncthreads();
        #pragma unroll
        for (int h = 0; h < 2; h++) {
            int cidx = h * 256 + tid;
            gl_lds16(&Xc[(size_t)(row0 + (cidx >> 2)) * DM + k0 + (cidx & 3) * 8],
                     &As[(size_t)(h * 256 + wave * 64) * 8]);
        }
        // B: 64 rows x 32 cols = 4KB = one 256-lane round
        gl_lds16(&Wfb[(size_t)(col0 + (tid >> 2)) * DM + k0 + (tid & 3) * 8],
                 &Bs[(size_t)(wave * 64) * 8]);
        __syncthreads();

        bf16x8 a[4], bfr[2];
        #pragma unroll
        for (int i = 0; i < 4; i++) a[i]   = *(const bf16x8*)&As[(wm + i * 16 + c16) * 32 + g8];
        #pragma unroll
        for (int i = 0; i < 2; i++) bfr[i] = *(const bf16x8*)&Bs[(wn + i * 16 + c16) * 32 + g8];
        #pragma unroll
        for (int mi = 0; mi < 4; mi++)
            #pragma unroll
            for (int ni = 0; ni < 2; ni++)
                acc[mi][ni] = __builtin_amdgcn_mfma_f32_16x16x32_bf16(a[mi], bfr[ni], acc[mi][ni], 0, 0, 0);
    }

    #pragma unroll
    for (int mi = 0; mi < 4; mi++) {
        int r0 = row0 + wm + mi * 16 + (lane >> 4) * 4;
        #pragma unroll
        for (int ni = 0; ni < 2; ni++) {
            int col = col0 + wn + ni * 16 + c16;
            float bsv = bias[col];
            #pragma unroll
            for (int i = 0; i < 4; i++)
                out[(size_t)(r0 + i) * DM + col] = acc[mi][ni][i] + bsv;
        }
    }
}

// ======================================================================
// FALLBACK GEMMs (known-good, ws = 67 MB)
// ======================================================================
__global__ __launch_bounds__(256) void gemm_qk(
    const __bf16* __restrict__ qb, const __bf16* __restrict__ kb,
    const float* __restrict__ wqf, const float* __restrict__ wkf,
    const float* __restrict__ bq, const float* __restrict__ bk,
    __bf16* __restrict__ Qp, __bf16* __restrict__ Kp)
{
    const int z = blockIdx.z;
    const __bf16* X = z ? kb : qb;
    const float* W  = z ? wkf : wqf;
    const float* bias = z ? bk : bq;
    __bf16* O = z ? Kp : Qp;
    const float qsc = z ? 1.0f : QSCALE;

    __shared__ __align__(16) __bf16 As[128 * 32];
    __shared__ __align__(16) __bf16 Bs[128 * 32];

    const int tid  = threadIdx.x;
    const int lane = tid & 63;
    const int wave = tid >> 6;
    const int wm = (wave >> 1) * 64;
    const int wn = (wave & 1) * 64;
    const int c16 = lane & 15;
    const int g8  = (lane >> 4) * 8;
    const int row0 = blockIdx.x * 128;
    const int col0 = blockIdx.y * 128;
    const int brow = tid >> 1;
    const int bcc  = (tid & 1) * 16;

    f32x4 acc[4][4] = {};
    for (int k0 = 0; k0 < DM; k0 += 32) {
        __syncthreads();
        #pragma unroll
        for (int h = 0; h < 2; h++) {
            int cidx = h * 256 + tid;
            gl_lds16(&X[(size_t)(row0 + (cidx >> 2)) * DM + k0 + (cidx & 3) * 8],
                     &As[(size_t)(h * 256 + wave * 64) * 8]);
        }
        *(bf16x8*)&Bs[brow * 32 + bcc]     = cvt8(&W[(size_t)(col0 + brow) * DM + k0 + bcc]);
        *(bf16x8*)&Bs[brow * 32 + bcc + 8] = cvt8(&W[(size_t)(col0 + brow) * DM + k0 + bcc + 8]);
        __syncthreads();

        bf16x8 a[4], bfr[4];
        #pragma unroll
        for (int i = 0; i < 4; i++) a[i]   = *(const bf16x8*)&As[(wm + i * 16 + c16) * 32 + g8];
        #pragma unroll
        for (int i = 0; i < 4; i++) bfr[i] = *(const bf16x8*)&Bs[(wn + i * 16 + c16) * 32 + g8];
        #pragma unroll
        for (int mi = 0; mi < 4; mi++)
            #pragma unroll
            for (int ni = 0; ni < 4; ni++)
                acc[mi][ni] = __builtin_amdgcn_mfma_f32_16x16x32_bf16(a[mi], bfr[ni], acc[mi][ni], 0, 0, 0);
    }

    #pragma unroll
    for (int mi = 0; mi < 4; mi++) {
        int r0 = row0 + wm + mi * 16 + (lane >> 4) * 4;
        #pragma unroll
        for (int ni = 0; ni < 4; ni++) {
            int col = col0 + wn + ni * 16 + c16;
            float bsv = bias[col];
            int h = col >> 6, d = col & 63;
            #pragma unroll
            for (int i = 0; i < 4; i++) {
                int r = r0 + i; int b = r >> 11, s = r & 2047;
                O[((size_t)(b * NH + h) * SEQ + s) * HD + d] = (__bf16)((acc[mi][ni][i] + bsv) * qsc);
            }
        }
    }
}

__global__ __launch_bounds__(256) void gemm_v(
    const float* __restrict__ vf, const float* __restrict__ wvf,
    const float* __restrict__ bv, __bf16* __restrict__ Vt)
{
    __shared__ __align__(16) __bf16 As[128 * 32];
    __shared__ __align__(16) __bf16 Bs[128 * 32];

    const int tid  = threadIdx.x;
    const int lane = tid & 63;
    const int wave = tid >> 6;
    const int wm = (wave >> 1) * 64;
    const int wn = (wave & 1) * 64;
    const int c16 = lane & 15;
    const int g8  = (lane >> 4) * 8;
    const int row0 = blockIdx.x * 128;
    const int col0 = blockIdx.y * 128;
    const int brow = tid >> 1;
    const int bcc  = (tid & 1) * 16;

    f32x4 acc[4][4] = {};
    for (int k0 = 0; k0 < DM; k0 += 32) {
        __syncthreads();
        *(bf16x8*)&As[brow * 32 + bcc]     = cvt8(&vf[(size_t)(row0 + brow) * DM + k0 + bcc]);
        *(bf16x8*)&As[brow * 32 + bcc + 8] = cvt8(&vf[(size_t)(row0 + brow) * DM + k0 + bcc + 8]);
        *(bf16x8*)&Bs[brow * 32 + bcc]     = cvt8(&wvf[(size_t)(col0 + brow) * DM + k0 + bcc]);
        *(bf16x8*)&Bs[brow * 32 + bcc + 8] = cvt8(&wvf[(size_t)(col0 + brow) * DM + k0 + bcc + 8]);
        __syncthreads();

        bf16x8 a[4], bfr[4];
        #pragma unroll
        for (int i = 0; i < 4; i++) a[i]   = *(const bf16x8*)&As[(wm + i * 16 + c16) * 32 + g8];
        #pragma unroll
        for (int i = 0; i < 4; i++) bfr[i] = *(const bf16x8*)&Bs[(wn + i * 16 + c16) * 32 + g8];
        #pragma unroll
        for (int mi = 0; mi < 4; mi++)
            #pragma unroll
            for (int ni = 0; ni < 4; ni++)
                acc[mi][ni] = __builtin_amdgcn_mfma_f32_16x16x32_bf16(a[mi], bfr[ni], acc[mi][ni], 0, 0, 0);
    }

    #pragma unroll
    for (int mi = 0; mi < 4; mi++) {
        int r0 = row0 + wm + mi * 16 + (lane >> 4) * 4;
        #pragma unroll
        for (int ni = 0; ni < 4; ni++) {
            int col = col0 + wn + ni * 16 + c16;
            float bsv = bv[col];
            int h = col >> 6, d = col & 63;
            int b = r0 >> 11, s0 = r0 & 2047;
            size_t base = ((size_t)((b * NH + h) * HD + d)) * SEQ + s0;
            #pragma unroll
            for (int i = 0; i < 4; i++)
                Vt[base + i] = (__bf16)(acc[mi][ni][i] + bsv);
        }
    }
}

__global__ __launch_bounds__(256) void gemm_fc(
    const __bf16* __restrict__ Xc, const float* __restrict__ Wf,
    const float* __restrict__ bias, float* __restrict__ out)
{
    __shared__ __align__(16) __bf16 As[128 * 32];
    __shared__ __align__(16) __bf16 Bs[128 * 32];

    const int tid  = threadIdx.x;
    const int lane = tid & 63;
    const int wave = tid >> 6;
    const int wm = (wave >> 1) * 64;
    const int wn = (wave & 1) * 64;
    const int c16 = lane & 15;
    const int g8  = (lane >> 4) * 8;
    const int row0 = blockIdx.x * 128;
    const int col0 = blockIdx.y * 128;
    const int brow = tid >> 1;
    const int bcc  = (tid & 1) * 16;

    f32x4 acc[4][4] = {};
    for (int k0 = 0; k0 < DM; k0 += 32) {
        __syncthreads();
        #pragma unroll
        for (int h = 0; h < 2; h++) {
            int cidx = h * 256 + tid;
            gl_lds16(&Xc[(size_t)(row0 + (cidx >> 2)) * DM + k0 + (cidx & 3) * 8],
                     &As[(size_t)(h * 256 + wave * 64) * 8]);
        }
        *(bf16x8*)&Bs[brow * 32 + bcc]     = cvt8(&Wf[(size_t)(col0 + brow) * DM + k0 + bcc]);
        *(bf16x8*)&Bs[brow * 32 + bcc + 8] = cvt8(&Wf[(size_t)(col0 + brow) * DM + k0 + bcc + 8]);
        __syncthreads();

        bf16x8 a[4], bfr[4];
        #pragma unroll
        for (int i = 0; i < 4; i++) a[i]   = *(const bf16x8*)&As[(wm + i * 16 + c16) * 32 + g8];
        #pragma unroll
        for (int i = 0; i < 4; i++) bfr[i] = *(const bf16x8*)&Bs[(wn + i * 16 + c16) * 32 + g8];
        #pragma unroll
        for (int mi = 0; mi < 4; mi++)
            #pragma unroll
            for (int ni = 0; ni < 4; ni++)
                acc[mi][ni] = __builtin_amdgcn_mfma_f32_16x16x32_bf16(a[mi], bfr[ni], acc[mi][ni], 0, 0, 0);
    }

    #pragma unroll
    for (int mi = 0; mi < 4; mi++) {
        int r0 = row0 + wm + mi * 16 + (lane >> 4) * 4;
        #pragma unroll
        for (int ni = 0; ni < 4; ni++) {
            int col = col0 + wn + ni * 16 + c16;
            float bsv = bias[col];
            #pragma unroll
            for (int i = 0; i < 4; i++)
                out[(size_t)(r0 + i) * DM + col] = acc[mi][ni][i] + bsv;
        }
    }
}

// ======================================================================
// flash attention (S^T / O^T), XOR-swizzled LDS, one-pass softmax.
// R9 structure (16x16 MFMA, 4-wave, QSCALE fold, transposed grid,
// permuted-k PV contract — no Ps buffer) + K/V DOUBLE-BUFFER:
//   Ps elimination dropped LDS to 16 KB, so dbuf now costs only 32 KB
//   (R7's failed dbuf was 48 KB -> occupancy 24%; here LDS cap = 5
//   blocks/CU >= the 4 resident -> no occupancy loss). Prologue stages
//   tile 0; each iter: sync (drains prefetch via vmcnt(0)@barrier) ->
//   issue prefetch(t+1, buf^1) -> compute(buf). Staging latency hides
//   under a full tile of QK/softmax/PV.
// No setprio: R10 A/B showed it slightly negative on this lockstep loop.
// grid (B*H, SEQ/128), block 256 = 4 waves; wave owns 32 queries.
// ======================================================================
__global__ __launch_bounds__(256, 4) void attn_kernel(
    const __bf16* __restrict__ Qp, const __bf16* __restrict__ Kp,
    const __bf16* __restrict__ Vt, __bf16* __restrict__ ctx)
{
    __shared__ __align__(16) __bf16 Ks[2][64 * 64];     // [key][d], swizzled, dbuf
    __shared__ __align__(16) __bf16 Vs[2][64 * 64];     // [d][key], swizzled, dbuf

    const int tid  = threadIdx.x;
    const int lane = tid & 63;
    const int w    = tid >> 6;
    const int bh   = blockIdx.x;                        // head index (XCD-local)
    const int q0   = blockIdx.y * 128 + w * 32;

    const __bf16* Qb = Qp + (size_t)bh * SEQ * HD;
    const __bf16* Kb = Kp + (size_t)bh * SEQ * HD;
    const __bf16* Vb = Vt + (size_t)bh * HD * SEQ;

    const int c16 = lane & 15;
    const int g   = lane >> 4;
    const int sw  = c16 & 7;    // swizzle key for this lane's frag rows

    // Q as B-fragment of Q^T: lane holds Q[query=c16][k = kc*32 + g*8 + j]
    bf16x8 qf[2][2];
    #pragma unroll
    for (int qs = 0; qs < 2; qs++)
        #pragma unroll
        for (int kc = 0; kc < 2; kc++)
            qf[qs][kc] = *(const bf16x8*)&Qb[(size_t)(q0 + qs * 16 + c16) * HD + kc * 32 + g * 8];

    float lp[2] = {0.f, 0.f};
    f32x4 o[4][2] = {};                 // O^T: row d = t*16+g*4+i, col query = c16

    // GLDS staging: wave w stages rows w*16 .. w*16+15 of Ks and Vs.
    const int srow = (w * 16) + (lane >> 3);          // +8 for h=1
    const int sj   = (lane & 7) ^ (lane >> 3);        // logical chunk (XOR swizzle)

    auto stage = [&](int kt, int buf) {
        const int k0 = kt * 64;
        #pragma unroll
        for (int h = 0; h < 2; h++) {
            int r = srow + h * 8;
            gl_lds16(&Kb[(size_t)(k0 + r) * HD + sj * 8], &Ks[buf][(size_t)(w * 16 + h * 8) * 64]);
            gl_lds16(&Vb[(size_t)r * SEQ + k0 + sj * 8],  &Vs[buf][(size_t)(w * 16 + h * 8) * 64]);
        }
    };

    const int NT = SEQ / 64;
    stage(0, 0);
    int cur = 0;

    for (int kt = 0; kt < NT; kt++) {
        __syncthreads();                           // drains vmcnt(0): buf[cur] ready
        if (kt + 1 < NT) stage(kt + 1, cur ^ 1);   // prefetch hides under compute

        const __bf16* ksb = &Ks[cur][0];
        const __bf16* vsb = &Vs[cur][0];

        // S^T = K · Q^T : rows = keys, cols = queries
        f32x4 sc[4][2] = {};
        #pragma unroll
        for (int t = 0; t < 4; t++) {
            #pragma unroll
            for (int kc = 0; kc < 2; kc++) {
                bf16x8 kf = *(const bf16x8*)&ksb[(t * 16 + c16) * 64 + ((kc * 4 + g) ^ sw) * 8];
                sc[t][0] = __builtin_amdgcn_mfma_f32_16x16x32_bf16(kf, qf[0][kc], sc[t][0], 0, 0, 0);
                sc[t][1] = __builtin_amdgcn_mfma_f32_16x16x32_bf16(kf, qf[1][kc], sc[t][1], 0, 0, 0);
            }
        }

        // softmax + permuted-k B-frag pack, fully in-register:
        // pf[qs][kc][j] = exp2(sc[2kc + (j>=4)][qs][j&3])
        bf16x8 pf[2][2];
        #pragma unroll
        for (int qs = 0; qs < 2; qs++) {
            float ps = 0.f;
            #pragma unroll
            for (int kc = 0; kc < 2; kc++) {
                bf16x8 pv8;
                #pragma unroll
                for (int i = 0; i < 4; i++) {
                    float pv = exp2f(sc[2 * kc][qs][i]);
                    ps += pv; pv8[i] = (__bf16)pv;
                }
                #pragma unroll
                for (int i = 0; i < 4; i++) {
                    float pv = exp2f(sc[2 * kc + 1][qs][i]);
                    ps += pv; pv8[4 + i] = (__bf16)pv;
                }
                pf[qs][kc] = pv8;
            }
            lp[qs] += ps;
        }

        // O^T += V^T · P^T with permuted-k A reads:
        // slot (g, j<4)  -> key kc*32 + 4g + j    (chunk kc*4+(g>>1),   elem (g&1)*4)
        // slot (g, j>=4) -> key kc*32 + 16+4g+j-4 (chunk kc*4+2+(g>>1), elem (g&1)*4)
        #pragma unroll
        for (int t = 0; t < 4; t++) {
            #pragma unroll
            for (int kc = 0; kc < 2; kc++) {
                union { bf16x8 v8; bf16x4 v4[2]; } u;
                u.v4[0] = *(const bf16x4*)&vsb[(t * 16 + c16) * 64 + (((kc * 4 + (g >> 1)) ^ sw) * 8) + (g & 1) * 4];
                u.v4[1] = *(const bf16x4*)&vsb[(t * 16 + c16) * 64 + (((kc * 4 + 2 + (g >> 1)) ^ sw) * 8) + (g & 1) * 4];
                o[t][0] = __builtin_amdgcn_mfma_f32_16x16x32_bf16(u.v8, pf[0][kc], o[t][0], 0, 0, 0);
                o[t][1] = __builtin_amdgcn_mfma_f32_16x16x32_bf16(u.v8, pf[1][kc], o[t][1], 0, 0, 0);
            }
        }

        cur ^= 1;
    }

    // finalize: reduce l over the 4 g-lanes, normalize, write ctx
    const int hh = bh & (NH - 1);
    const int bb = bh >> 4;
    #pragma unroll
    for (int qs = 0; qs < 2; qs++) {
        float l = lp[qs];
        l += __shfl_xor(l, 16, 64);
        l += __shfl_xor(l, 32, 64);
        float inv = 1.f / l;
        int s = q0 + qs * 16 + c16;
        #pragma unroll
        for (int t = 0; t < 4; t++) {
            bf16x4 ov;
            #pragma unroll
            for (int i = 0; i < 4; i++) ov[i] = (__bf16)(o[t][qs][i] * inv);
            *(bf16x4*)&ctx[((size_t)(bb * SEQ + s)) * DM + hh * HD + t * 16 + g * 4] = ov;
        }
    }
}

// ---------------- launch ----------------
extern "C" void kernel_launch(void* const* d_in, const int* in_sizes, int n_in,
                              void* d_out, int out_size, void* d_ws, size_t ws_size,
                              hipStream_t stream) {
    const float* q    = (const float*)d_in[0];
    const float* k    = (const float*)d_in[1];
    const float* v    = (const float*)d_in[2];
    const float* w_q  = (const float*)d_in[3];
    const float* b_q  = (const float*)d_in[4];
    const float* w_k  = (const float*)d_in[5];
    const float* b_k  = (const float*)d_in[6];
    const float* w_v  = (const float*)d_in[7];
    const float* b_v  = (const float*)d_in[8];
    const float* w_fc = (const float*)d_in[9];
    const float* b_fc = (const float*)d_in[10];
    float* out = (float*)d_out;

    // qb,kb live in d_out (dead before gemm_fc writes it)
    __bf16* qb = (__bf16*)d_out;
    __bf16* kb = qb + (size_t)ROWS * DM;

    char* p = (char*)d_ws;
    auto alloc = [&](size_t bytes) { char* r = p; p += (bytes + 255) & ~(size_t)255; return r; };
    const size_t XSZ = (size_t)ROWS * DM * 2;   // 16.78 MB
    const size_t WSZ = (size_t)DM * DM * 2;     // 2.10 MB

    __bf16* Qp  = (__bf16*)alloc(XSZ);
    __bf16* Kp  = (__bf16*)alloc(XSZ);
    __bf16* Vt  = (__bf16*)alloc(XSZ);
    __bf16* ctx = (__bf16*)alloc(XSZ);

    const size_t base_need = (size_t)(p - (char*)d_ws);
    const size_t fast_need = base_need + 4 * (WSZ + 256);

    const int n8x = ROWS * DM / 8;   // 1,048,576
    const int n8w = DM * DM / 8;     // 131,072

    // vb lives in the ctx region: dead before attn writes ctx, and does NOT
    // alias Qp -> enables the single merged QKV projection launch.
    __bf16* vb = ctx;

    // q,k -> d_out region; v -> ctx region (one merged launch)
    cast3<<<dim3(n8x / 256, 3), 256, 0, stream>>>(q, k, v, qb, kb, vb, n8x);

    if (ws_size >= fast_need) {
        // FAST PATH: bf16 weights in ws, all GEMMs all-GLDS.
        __bf16* wqb  = (__bf16*)alloc(WSZ);
        __bf16* wkb  = (__bf16*)alloc(WSZ);
        __bf16* wvb  = (__bf16*)alloc(WSZ);
        __bf16* wfcb = (__bf16*)alloc(WSZ);

        cast4<<<dim3(n8w / 256, 4), 256, 0, stream>>>(
            w_q, w_k, w_v, w_fc, wqb, wkb, wvb, wfcb, n8w);

        // merged Q/K/V projections: one 1536-block launch (6 blocks/CU)
        gemm_qkv_f<<<dim3(ROWS / 128, DM / 128, 3), 256, 0, stream>>>(
            qb, kb, vb, wqb, wkb, wvb, b_q, b_k, b_v, Qp, Kp, Vt);

        // grid: x = head (XCD-local K/V), y = q-block (128 queries)
        attn_kernel<<<dim3(BN * NH, SEQ / 128), 256, 0, stream>>>(Qp, Kp, Vt, ctx);

        // FC: 128x64 tiles -> 1024 blocks (4/CU)
        gemm_fc_f<<<dim3(ROWS / 128, DM / 64), 256, 0, stream>>>(ctx, wfcb, b_fc, out);
    } else {
        // FALLBACK (67 MB ws)
        gemm_v<<<dim3(ROWS / 128, DM / 128), 256, 0, stream>>>(v, w_v, b_v, Vt);
        gemm_qk<<<dim3(ROWS / 128, DM / 128, 2), 256, 0, stream>>>(
            qb, kb, w_q, w_k, b_q, b_k, Qp, Kp);

        attn_kernel<<<dim3(BN * NH, SEQ / 128), 256, 0, stream>>>(Qp, Kp, Vt, ctx);

        gemm_fc<<<dim3(ROWS / 128, DM / 128), 256, 0, stream>>>(ctx, w_fc, b_fc, out);
    }
}